// Round 3
// baseline (2128.091 us; speedup 1.0000x reference)
//
#include <hip/hip_runtime.h>

// Forest-Ruth integrator via bf16x3-split MFMA (32x32x16), B=32768, D=512, K=64.
// Block = 32 rows, 512 threads (8 waves), grid 1024. 1 block/CU (LDS-bound).
// U/W: prep kernel splits fp32 -> bf16 hi/lo, swizzled to MFMA B-frag layout in
// d_ws. v/x state in registers (MFMA C/D layout); v round-trips LDS in A-frag
// layout.
//
// Register-pressure note (rounds 1-2 post-mortem): holding U+W fragments
// permanently (128 regs) + state (64) + acc (32) put the wave at ~244/256
// unified regs; any extra temp tipped the allocator into spilling a 64-reg
// fragment array to scratch (FETCH 255MB -> 1.1GB: 32 dwords stored once,
// reloaded 12x). Fix: U and W fragments are now RELOADED from global (L2-
// resident, 256KB shared) each substep — W right after GEMM1 (latency hidden
// under atomics+B1+g+B2), U in the epilogue (hidden under vf_stores+B0).
// Opaque-pointer asm per iteration prevents re-hoisting into permanent regs.
// Peak pressure ~180 regs. GEMM math and accumulation order byte-identical
// to the 1082us baseline.

#define NTH 512

// LDS word-offsets (4B words)
#define VF0 0          // v-frag plane j0..3 : [32 kstep][64 slot][4 words], slot swizzled
#define VF1 8192       // v-frag plane j4..7
#define GF0 16384      // g-frag plane j0..3 : [4 kstep][64 slot][4 words], slot swizzled
#define GF1 17408      // g-frag plane j4..7
#define HB  18432      // h buffer fp32 [32][68]
#define FB  20608      // f buffer fp32 [32][516]
#define LDS_WORDS 37120
#define LDS_BYTES (LDS_WORDS*4)   // 148480 B

typedef __attribute__((ext_vector_type(8))) short short8;
typedef __attribute__((ext_vector_type(16))) float float16;

__device__ __forceinline__ float wrap_torus(float y) {
    const float PI_F  = 3.14159265358979323846f;
    const float TPI_F = 6.28318530717958647692f;
    float t = y + PI_F;
    if (t >= TPI_F) t -= TPI_F;
    else if (t < 0.0f) t += TPI_F;
    return t - PI_F;
}

__device__ __forceinline__ void split2(float v, unsigned short& hi, unsigned short& lo) {
    unsigned u = __float_as_uint(v);
    unsigned h = (u + 0x7fffu + ((u >> 16) & 1u)) >> 16;    // RNE to bf16
    hi = (unsigned short)h;
    float hf = __uint_as_float(h << 16);
    float r = v - hf;                                        // exact
    unsigned u2 = __float_as_uint(r);
    unsigned l = (u2 + 0x7fffu + ((u2 >> 16) & 1u)) >> 16;
    lo = (unsigned short)l;
}

__device__ __forceinline__ unsigned pack_split(float v) {
    unsigned short hi, lo;
    split2(v, hi, lo);
    return (((unsigned)hi) << 16) | (unsigned)lo;
}

__device__ __forceinline__ void unpack_frag(uint4 l4, uint4 h4, short8& fhi, short8& flo) {
    fhi[0]=(short)(l4.x>>16); flo[0]=(short)(l4.x&0xffffu);
    fhi[1]=(short)(l4.y>>16); flo[1]=(short)(l4.y&0xffffu);
    fhi[2]=(short)(l4.z>>16); flo[2]=(short)(l4.z&0xffffu);
    fhi[3]=(short)(l4.w>>16); flo[3]=(short)(l4.w&0xffffu);
    fhi[4]=(short)(h4.x>>16); flo[4]=(short)(h4.x&0xffffu);
    fhi[5]=(short)(h4.y>>16); flo[5]=(short)(h4.y&0xffffu);
    fhi[6]=(short)(h4.z>>16); flo[6]=(short)(h4.z&0xffffu);
    fhi[7]=(short)(h4.w>>16); flo[7]=(short)(h4.w&0xffffu);
}

// Bijective slot swizzle (6-bit): fold lb (bit5) into quad-bit1 and kst low
// bits into quad-bits 0/1. Store uses swz(m+32*lb, kst); read uses swz(lane,
// kst) — same permutation per (kst, plane), so data round-trips exactly.
__device__ __forceinline__ int swz(int s, int kst) {
    return s ^ ((s >> 5) << 1) ^ (kst & 3);
}

__device__ __forceinline__ void vf_store(unsigned int* ldsu, int m, int d, unsigned p) {
    int kst = d >> 4, lb = (d >> 3) & 1, j = d & 7;
    int slot = swz(m + 32 * lb, kst);
    ldsu[((j >> 2) ? VF1 : VF0) + (kst * 64 + slot) * 4 + (j & 3)] = p;
}

// ---- prep: split U, W to bf16 hi/lo in MFMA B-frag swizzled layout in d_ws.
// U frag (nt1,ks4,c): B[k][n]: n = 32*nt1 + (lane&31), d = 128*ks4+16*c+8*(lane>>5)+j
// W frag (nt,kk):     B[k][n]: n = 32*nt  + (lane&31), k = 16*kk+8*(lane>>5)+j
__global__ void fr_prep(const float* __restrict__ Um, const float* __restrict__ Wm,
                        unsigned short* __restrict__ usw, unsigned short* __restrict__ wsw) {
    int tid = blockIdx.x * 256 + threadIdx.x;   // 8192 total
    int lane = tid & 63;
    if (tid < 4096) {
        int c   = (tid >> 6) & 7;
        int ks4 = (tid >> 9) & 3;
        int nt1 = (tid >> 11) & 1;
        int fbase = (((nt1 * 4 + ks4) * 8 + c) * 2) * 512;   // ushort units
        #pragma unroll
        for (int j = 0; j < 8; ++j) {
            int d = 128 * ks4 + 16 * c + 8 * (lane >> 5) + j;
            int n = 32 * nt1 + (lane & 31);
            unsigned short hi, lo;
            split2(Um[d * 64 + n], hi, lo);
            usw[fbase + lane * 8 + j] = hi;
            usw[fbase + 512 + lane * 8 + j] = lo;
        }
    } else {
        int id = tid - 4096;
        lane = id & 63;
        int kk = (id >> 6) & 3;
        int nt = (id >> 8) & 15;
        int fbase = ((nt * 4 + kk) * 2) * 512;
        #pragma unroll
        for (int j = 0; j < 8; ++j) {
            int k = 16 * kk + 8 * (lane >> 5) + j;
            int n = 32 * nt + (lane & 31);
            unsigned short hi, lo;
            split2(Wm[k * 512 + n], hi, lo);
            wsw[fbase + lane * 8 + j] = hi;
            wsw[fbase + 512 + lane * 8 + j] = lo;
        }
    }
}

__global__ __launch_bounds__(NTH, 2) void fr_mfma(
    const float* __restrict__ xin, const float* __restrict__ vin,
    const float* __restrict__ fin,
    const short8* __restrict__ usw, const short8* __restrict__ wsw,
    float* __restrict__ xout, float* __restrict__ vout)
{
    extern __shared__ float lds[];
    unsigned int* ldsu = (unsigned int*)lds;

    const int t = threadIdx.x;
    const int lane = t & 63;
    const int w = __builtin_amdgcn_readfirstlane(t >> 6);    // 0..7
    const int nt1 = w & 1;       // GEMM1 h-col tile
    const int ks4 = w >> 1;      // GEMM1 k-split (d range 128*ks4..+128)
    const int rhalf = lane >> 5;
    const int R0 = (int)blockIdx.x * 32;

    const double theta = 1.0 / (2.0 - 1.2599210498948732);
    const float c1dt = (float)(theta * 0.5 * 0.01);
    const float c2dt = (float)((1.0 - theta) * 0.5 * 0.01);
    const float d1dt = (float)(theta * 0.01);
    const float d2dt = (float)((1.0 - 2.0 * theta) * 0.01);

    // ---- operand fragments (U: prologue + per-substep reload in epilogue;
    //      W: reloaded in-loop after GEMM1). Opaque bases defeat hoisting.
    short8 Uhi[8], Ulo[8], Whi[2][4], Wlo[2][4];
    uintptr_t uop = (uintptr_t)usw;
    uintptr_t wop = (uintptr_t)wsw;
    const int ub = ((nt1 * 4 + ks4) * 8) * 2;   // U frag base (short8 units of 64)
    {
        const short8* up = (const short8*)uop;
        #pragma unroll
        for (int c = 0; c < 8; ++c) {
            Uhi[c] = up[(ub + 2 * c + 0) * 64 + lane];
            Ulo[c] = up[(ub + 2 * c + 1) * 64 + lane];
        }
    }

    // ---- state registers in C/D layout: col = 32*(2w+nt)+(lane&31),
    //      row = (r&3)+8*(r>>2)+4*rhalf
    float vst[2][16], xst[2][16];
    int cg[2];
    cg[0] = (w * 2 + 0) * 32 + (lane & 31);
    cg[1] = (w * 2 + 1) * 32 + (lane & 31);
    #pragma unroll
    for (int nt = 0; nt < 2; ++nt) {
        #pragma unroll
        for (int r = 0; r < 16; ++r) {
            int rrow = (r & 3) + 8 * (r >> 2) + 4 * rhalf;
            size_t idx = (size_t)(R0 + rrow) * 512 + cg[nt];
            vst[nt][r] = vin[idx];
            xst[nt][r] = xin[idx];
        }
    }

    // ---- stage f into LDS [32][516]
    {
        #pragma unroll
        for (int it = 0; it < 8; ++it) {
            int flat = it * 2048 + t * 4;
            float4 val = *(const float4*)(fin + (size_t)R0 * 512 + flat);
            int row = flat >> 9, col = flat & 511;
            *(float4*)(lds + FB + row * 516 + col) = val;
        }
    }

    // ---- x1 = wrap(x + c1dt*v)
    #pragma unroll
    for (int nt = 0; nt < 2; ++nt)
        #pragma unroll
        for (int r = 0; r < 16; ++r)
            xst[nt][r] = wrap_torus(xst[nt][r] + c1dt * vst[nt][r]);

    // ---- write v0 splits to vfrag; zero hbuf (once; thereafter g-phase
    //      read-then-zero keeps it clean, ordered by B2)
    #pragma unroll
    for (int nt = 0; nt < 2; ++nt) {
        #pragma unroll
        for (int r = 0; r < 16; ++r) {
            int m = (r & 3) + 8 * (r >> 2) + 4 * rhalf;
            vf_store(ldsu, m, cg[nt], pack_split(vst[nt][r]));
        }
    }
    for (int i = t; i < 32 * 68; i += NTH) lds[HB + i] = 0.0f;

    #pragma unroll 1
    for (int sub = 0; sub < 12; ++sub) {
        const int idx3 = sub - (sub / 3) * 3;
        const float ddt = (idx3 == 1) ? d2dt : d1dt;
        const float xc  = (idx3 == 2) ? c1dt : c2dt;
        const bool dbl  = (idx3 == 2) && (sub != 11);

        __syncthreads();   // B0: vfrag writes complete

        // ---- GEMM1: h-tile(nt1), d in [128*ks4, +128), 3-pass bf16x3
        float16 acc0, acc1;
        #pragma unroll
        for (int i = 0; i < 16; ++i) { acc0[i] = 0.0f; acc1[i] = 0.0f; }
        #pragma unroll
        for (int c = 0; c < 8; ++c) {
            int kst = ks4 * 8 + c;
            int slot = swz(lane, kst);
            uint4 pl = *(const uint4*)&ldsu[VF0 + (kst * 64 + slot) * 4];
            uint4 ph = *(const uint4*)&ldsu[VF1 + (kst * 64 + slot) * 4];
            short8 Ahi, Alo;
            unpack_frag(pl, ph, Ahi, Alo);
            acc0 = __builtin_amdgcn_mfma_f32_32x32x16_bf16(Ahi, Uhi[c], acc0, 0, 0, 0);
            acc1 = __builtin_amdgcn_mfma_f32_32x32x16_bf16(Alo, Uhi[c], acc1, 0, 0, 0);
            acc1 = __builtin_amdgcn_mfma_f32_32x32x16_bf16(Ahi, Ulo[c], acc1, 0, 0, 0);
        }

        // ---- issue W fragment loads for this substep's GEMM2 (L2-resident;
        //      latency hidden under atomics + B1 + g-phase + B2)
        asm volatile("" : "+s"(wop));
        {
            const short8* wp = (const short8*)wop;
            #pragma unroll
            for (int nt = 0; nt < 2; ++nt) {
                int wb = ((w * 2 + nt) * 4) * 2;
                #pragma unroll
                for (int kk = 0; kk < 4; ++kk) {
                    Whi[nt][kk] = wp[(wb + 2 * kk + 0) * 64 + lane];
                    Wlo[nt][kk] = wp[(wb + 2 * kk + 1) * 64 + lane];
                }
            }
        }

        {
            int kcol = nt1 * 32 + (lane & 31);
            #pragma unroll
            for (int r = 0; r < 16; ++r) {
                int m = (r & 3) + 8 * (r >> 2) + 4 * rhalf;
                atomicAdd(&lds[HB + m * 68 + kcol], acc0[r] + acc1[r]);
            }
        }
        __syncthreads();   // B1: h complete

        // ---- g = h*h, split, write g-frags (one b128); zero h cell for next sub
        {
            int grow = t >> 4;
            int k4 = (t & 15) * 4;
            float4 h4 = *(const float4*)&lds[HB + grow * 68 + k4];
            float4 z4; z4.x = 0.0f; z4.y = 0.0f; z4.z = 0.0f; z4.w = 0.0f;
            *(float4*)&lds[HB + grow * 68 + k4] = z4;   // read-then-zero (thread-private cell)
            uint4 gp;
            gp.x = pack_split(h4.x * h4.x);
            gp.y = pack_split(h4.y * h4.y);
            gp.z = pack_split(h4.z * h4.z);
            gp.w = pack_split(h4.w * h4.w);
            int kst2 = k4 >> 4, lb2 = (k4 >> 3) & 1, jb = k4 & 7;
            int slot2 = swz(grow + 32 * lb2, kst2);
            *(uint4*)&ldsu[((jb >> 2) ? GF1 : GF0) + (kst2 * 64 + slot2) * 4] = gp;
        }
        __syncthreads();   // B2: g-frags ready (also orders HB zero before next atomics)

        // ---- GEMM2: christ tiles 2w, 2w+1 over K=64
        float16 cA, cB;
        #pragma unroll
        for (int i = 0; i < 16; ++i) { cA[i] = 0.0f; cB[i] = 0.0f; }
        #pragma unroll
        for (int kk = 0; kk < 4; ++kk) {
            int slot = swz(lane, kk);
            uint4 pl = *(const uint4*)&ldsu[GF0 + (kk * 64 + slot) * 4];
            uint4 ph = *(const uint4*)&ldsu[GF1 + (kk * 64 + slot) * 4];
            short8 Ahi, Alo;
            unpack_frag(pl, ph, Ahi, Alo);
            cA = __builtin_amdgcn_mfma_f32_32x32x16_bf16(Ahi, Whi[0][kk], cA, 0, 0, 0);
            cB = __builtin_amdgcn_mfma_f32_32x32x16_bf16(Ahi, Whi[1][kk], cB, 0, 0, 0);
            cA = __builtin_amdgcn_mfma_f32_32x32x16_bf16(Alo, Whi[0][kk], cA, 0, 0, 0);
            cB = __builtin_amdgcn_mfma_f32_32x32x16_bf16(Alo, Whi[1][kk], cB, 0, 0, 0);
            cA = __builtin_amdgcn_mfma_f32_32x32x16_bf16(Ahi, Wlo[0][kk], cA, 0, 0, 0);
            cB = __builtin_amdgcn_mfma_f32_32x32x16_bf16(Ahi, Wlo[1][kk], cB, 0, 0, 0);
        }

        // ---- epilogue: v += ddt*(f - christ); x = wrap(x + xc*v) (+ fused c1)
        #pragma unroll
        for (int nt = 0; nt < 2; ++nt) {
            #pragma unroll
            for (int r = 0; r < 16; ++r) {
                int m = (r & 3) + 8 * (r >> 2) + 4 * rhalf;
                float fv = lds[FB + m * 516 + cg[nt]];
                float christ = (nt == 0) ? cA[r] : cB[r];
                float vn = vst[nt][r] + ddt * (fv - christ);
                vst[nt][r] = vn;
                float xn = wrap_torus(xst[nt][r] + xc * vn);
                if (dbl) xn = wrap_torus(xn + c1dt * vn);
                xst[nt][r] = xn;
            }
        }

        if (sub != 11) {
            // ---- reissue U fragment loads for next substep's GEMM1 (latency
            //      hidden under vf_stores + B0 wait)
            asm volatile("" : "+s"(uop));
            {
                const short8* up = (const short8*)uop;
                #pragma unroll
                for (int c = 0; c < 8; ++c) {
                    Uhi[c] = up[(ub + 2 * c + 0) * 64 + lane];
                    Ulo[c] = up[(ub + 2 * c + 1) * 64 + lane];
                }
            }
            // ---- write new v splits for next substep
            #pragma unroll
            for (int nt = 0; nt < 2; ++nt) {
                #pragma unroll
                for (int r = 0; r < 16; ++r) {
                    int m = (r & 3) + 8 * (r >> 2) + 4 * rhalf;
                    vf_store(ldsu, m, cg[nt], pack_split(vst[nt][r]));
                }
            }
        }
    }

    // ---- store outputs
    #pragma unroll
    for (int nt = 0; nt < 2; ++nt) {
        #pragma unroll
        for (int r = 0; r < 16; ++r) {
            int rrow = (r & 3) + 8 * (r >> 2) + 4 * rhalf;
            size_t idx = (size_t)(R0 + rrow) * 512 + cg[nt];
            xout[idx] = xst[nt][r];
            vout[idx] = vst[nt][r];
        }
    }
}

extern "C" void kernel_launch(void* const* d_in, const int* in_sizes, int n_in,
                              void* d_out, int out_size, void* d_ws, size_t ws_size,
                              hipStream_t stream) {
    const float* x = (const float*)d_in[0];
    const float* v = (const float*)d_in[1];
    const float* f = (const float*)d_in[2];
    const float* U = (const float*)d_in[3];
    const float* W = (const float*)d_in[4];

    float* xout = (float*)d_out;
    float* vout = xout + (size_t)32768 * 512;

    unsigned short* usw = (unsigned short*)d_ws;               // 128 KiB
    unsigned short* wsw = usw + 65536;                          // 128 KiB

    fr_prep<<<32, 256, 0, stream>>>(U, W, usw, wsw);

    hipFuncSetAttribute(reinterpret_cast<const void*>(fr_mfma),
                        hipFuncAttributeMaxDynamicSharedMemorySize, LDS_BYTES);
    fr_mfma<<<1024, NTH, LDS_BYTES, stream>>>(
        x, v, f, (const short8*)usw, (const short8*)wsw, xout, vout);
}

// Round 4
// 1263.535 us; speedup vs baseline: 1.6842x; 1.6842x over previous
//
#include <hip/hip_runtime.h>

// Forest-Ruth integrator via bf16x3-split MFMA (32x32x16), B=32768, D=512, K=64.
// Block = 32 rows, 512 threads (8 waves), grid 1024. 1 block/CU (LDS-bound).
// U/W: prep kernel splits fp32 -> bf16 hi/lo, swizzled to MFMA B-frag layout in
// d_ws. v/x state in registers (MFMA C/D layout); v round-trips LDS in A-frag
// layout.
//
// Register-pressure design (rounds 1-3 post-mortem): U-frags (64 regs) and
// W-frags (64 regs) as separate persistent arrays put the wave at ~250/256
// unified regs; every source perturbation caused a 64-reg array to spill to
// scratch (FETCH 255MB -> 1.1-1.7GB). Fix: ONE short8 frag[16] array (64
// regs) TIME-SHARED between U and W. Epilogue loads U into frag (for next
// GEMM1); right after GEMM1, W is loaded into the SAME frag (for GEMM2).
// The allocator physically cannot keep both. Peak ~185 regs. Opaque-pointer
// asm per reload site defeats load-PRE (which would resurrect a hoisted
// second copy). Reloads are L1/L2-resident (12KB/CU/substep) and issued 2+
// barriers ahead of use. GEMM math byte-identical to the 1082us baseline.
// Kept from round 2: VF/GF slot swizzle (conflicts 5.35e7 -> 1.34e7) and
// HB read-then-zero in the g-phase.

#define NTH 512

// LDS word-offsets (4B words)
#define VF0 0          // v-frag plane j0..3 : [32 kstep][64 slot][4 words], slot swizzled
#define VF1 8192       // v-frag plane j4..7
#define GF0 16384      // g-frag plane j0..3 : [4 kstep][64 slot][4 words], slot swizzled
#define GF1 17408      // g-frag plane j4..7
#define HB  18432      // h buffer fp32 [32][68]
#define FB  20608      // f buffer fp32 [32][516]
#define LDS_WORDS 37120
#define LDS_BYTES (LDS_WORDS*4)   // 148480 B

typedef __attribute__((ext_vector_type(8))) short short8;
typedef __attribute__((ext_vector_type(16))) float float16;

__device__ __forceinline__ float wrap_torus(float y) {
    const float PI_F  = 3.14159265358979323846f;
    const float TPI_F = 6.28318530717958647692f;
    float t = y + PI_F;
    if (t >= TPI_F) t -= TPI_F;
    else if (t < 0.0f) t += TPI_F;
    return t - PI_F;
}

__device__ __forceinline__ void split2(float v, unsigned short& hi, unsigned short& lo) {
    unsigned u = __float_as_uint(v);
    unsigned h = (u + 0x7fffu + ((u >> 16) & 1u)) >> 16;    // RNE to bf16
    hi = (unsigned short)h;
    float hf = __uint_as_float(h << 16);
    float r = v - hf;                                        // exact
    unsigned u2 = __float_as_uint(r);
    unsigned l = (u2 + 0x7fffu + ((u2 >> 16) & 1u)) >> 16;
    lo = (unsigned short)l;
}

__device__ __forceinline__ unsigned pack_split(float v) {
    unsigned short hi, lo;
    split2(v, hi, lo);
    return (((unsigned)hi) << 16) | (unsigned)lo;
}

__device__ __forceinline__ void unpack_frag(uint4 l4, uint4 h4, short8& fhi, short8& flo) {
    fhi[0]=(short)(l4.x>>16); flo[0]=(short)(l4.x&0xffffu);
    fhi[1]=(short)(l4.y>>16); flo[1]=(short)(l4.y&0xffffu);
    fhi[2]=(short)(l4.z>>16); flo[2]=(short)(l4.z&0xffffu);
    fhi[3]=(short)(l4.w>>16); flo[3]=(short)(l4.w&0xffffu);
    fhi[4]=(short)(h4.x>>16); flo[4]=(short)(h4.x&0xffffu);
    fhi[5]=(short)(h4.y>>16); flo[5]=(short)(h4.y&0xffffu);
    fhi[6]=(short)(h4.z>>16); flo[6]=(short)(h4.z&0xffffu);
    fhi[7]=(short)(h4.w>>16); flo[7]=(short)(h4.w&0xffffu);
}

// Bijective slot swizzle (6-bit): fold lb (bit5) into quad-bit1 and kst low
// bits into quad-bits 0/1. Store uses swz(m+32*lb, kst); read uses swz(lane,
// kst) — same permutation per (kst, plane), so data round-trips exactly.
__device__ __forceinline__ int swz(int s, int kst) {
    return s ^ ((s >> 5) << 1) ^ (kst & 3);
}

__device__ __forceinline__ void vf_store(unsigned int* ldsu, int m, int d, unsigned p) {
    int kst = d >> 4, lb = (d >> 3) & 1, j = d & 7;
    int slot = swz(m + 32 * lb, kst);
    ldsu[((j >> 2) ? VF1 : VF0) + (kst * 64 + slot) * 4 + (j & 3)] = p;
}

// ---- prep: split U, W to bf16 hi/lo in MFMA B-frag swizzled layout in d_ws.
// U frag (nt1,ks4,c): B[k][n]: n = 32*nt1 + (lane&31), d = 128*ks4+16*c+8*(lane>>5)+j
// W frag (nt,kk):     B[k][n]: n = 32*nt  + (lane&31), k = 16*kk+8*(lane>>5)+j
__global__ void fr_prep(const float* __restrict__ Um, const float* __restrict__ Wm,
                        unsigned short* __restrict__ usw, unsigned short* __restrict__ wsw) {
    int tid = blockIdx.x * 256 + threadIdx.x;   // 8192 total
    int lane = tid & 63;
    if (tid < 4096) {
        int c   = (tid >> 6) & 7;
        int ks4 = (tid >> 9) & 3;
        int nt1 = (tid >> 11) & 1;
        int fbase = (((nt1 * 4 + ks4) * 8 + c) * 2) * 512;   // ushort units
        #pragma unroll
        for (int j = 0; j < 8; ++j) {
            int d = 128 * ks4 + 16 * c + 8 * (lane >> 5) + j;
            int n = 32 * nt1 + (lane & 31);
            unsigned short hi, lo;
            split2(Um[d * 64 + n], hi, lo);
            usw[fbase + lane * 8 + j] = hi;
            usw[fbase + 512 + lane * 8 + j] = lo;
        }
    } else {
        int id = tid - 4096;
        lane = id & 63;
        int kk = (id >> 6) & 3;
        int nt = (id >> 8) & 15;
        int fbase = ((nt * 4 + kk) * 2) * 512;
        #pragma unroll
        for (int j = 0; j < 8; ++j) {
            int k = 16 * kk + 8 * (lane >> 5) + j;
            int n = 32 * nt + (lane & 31);
            unsigned short hi, lo;
            split2(Wm[k * 512 + n], hi, lo);
            wsw[fbase + lane * 8 + j] = hi;
            wsw[fbase + 512 + lane * 8 + j] = lo;
        }
    }
}

__global__ __launch_bounds__(NTH, 2) void fr_mfma(
    const float* __restrict__ xin, const float* __restrict__ vin,
    const float* __restrict__ fin,
    const short8* __restrict__ usw, const short8* __restrict__ wsw,
    float* __restrict__ xout, float* __restrict__ vout)
{
    extern __shared__ float lds[];
    unsigned int* ldsu = (unsigned int*)lds;

    const int t = threadIdx.x;
    const int lane = t & 63;
    const int w = __builtin_amdgcn_readfirstlane(t >> 6);    // 0..7
    const int nt1 = w & 1;       // GEMM1 h-col tile
    const int ks4 = w >> 1;      // GEMM1 k-split (d range 128*ks4..+128)
    const int rhalf = lane >> 5;
    const int R0 = (int)blockIdx.x * 32;

    const double theta = 1.0 / (2.0 - 1.2599210498948732);
    const float c1dt = (float)(theta * 0.5 * 0.01);
    const float c2dt = (float)((1.0 - theta) * 0.5 * 0.01);
    const float d1dt = (float)(theta * 0.01);
    const float d2dt = (float)((1.0 - 2.0 * theta) * 0.01);

    // ---- ONE time-shared operand array: holds U-frags during GEMM1,
    //      W-frags during GEMM2. frag[2c]/frag[2c+1] = Uhi[c]/Ulo[c];
    //      frag[nt*8+2kk]/frag[nt*8+2kk+1] = Whi[nt][kk]/Wlo[nt][kk].
    short8 frag[16];
    uintptr_t uop = (uintptr_t)usw;
    uintptr_t wop = (uintptr_t)wsw;
    const int ub = (nt1 * 4 + ks4) * 16;   // U frag plane base (short8 units of 64)
    const int wb = w * 16;                 // W frag plane base
    {
        const short8* up = (const short8*)uop;
        #pragma unroll
        for (int i = 0; i < 16; ++i)
            frag[i] = up[(ub + i) * 64 + lane];
    }

    // ---- state registers in C/D layout: col = 32*(2w+nt)+(lane&31),
    //      row = (r&3)+8*(r>>2)+4*rhalf
    float vst[2][16], xst[2][16];
    int cg[2];
    cg[0] = (w * 2 + 0) * 32 + (lane & 31);
    cg[1] = (w * 2 + 1) * 32 + (lane & 31);
    #pragma unroll
    for (int nt = 0; nt < 2; ++nt) {
        #pragma unroll
        for (int r = 0; r < 16; ++r) {
            int rrow = (r & 3) + 8 * (r >> 2) + 4 * rhalf;
            size_t idx = (size_t)(R0 + rrow) * 512 + cg[nt];
            vst[nt][r] = vin[idx];
            xst[nt][r] = xin[idx];
        }
    }

    // ---- stage f into LDS [32][516]
    {
        #pragma unroll
        for (int it = 0; it < 8; ++it) {
            int flat = it * 2048 + t * 4;
            float4 val = *(const float4*)(fin + (size_t)R0 * 512 + flat);
            int row = flat >> 9, col = flat & 511;
            *(float4*)(lds + FB + row * 516 + col) = val;
        }
    }

    // ---- x1 = wrap(x + c1dt*v)
    #pragma unroll
    for (int nt = 0; nt < 2; ++nt)
        #pragma unroll
        for (int r = 0; r < 16; ++r)
            xst[nt][r] = wrap_torus(xst[nt][r] + c1dt * vst[nt][r]);

    // ---- write v0 splits to vfrag; zero hbuf (once; thereafter g-phase
    //      read-then-zero keeps it clean, ordered by B2)
    #pragma unroll
    for (int nt = 0; nt < 2; ++nt) {
        #pragma unroll
        for (int r = 0; r < 16; ++r) {
            int m = (r & 3) + 8 * (r >> 2) + 4 * rhalf;
            vf_store(ldsu, m, cg[nt], pack_split(vst[nt][r]));
        }
    }
    for (int i = t; i < 32 * 68; i += NTH) lds[HB + i] = 0.0f;

    #pragma unroll 1
    for (int sub = 0; sub < 12; ++sub) {
        const int idx3 = sub - (sub / 3) * 3;
        const float ddt = (idx3 == 1) ? d2dt : d1dt;
        const float xc  = (idx3 == 2) ? c1dt : c2dt;
        const bool dbl  = (idx3 == 2) && (sub != 11);

        __syncthreads();   // B0: vfrag writes complete

        // ---- GEMM1: h-tile(nt1), d in [128*ks4, +128), 3-pass bf16x3
        //      (frag holds U: hi at frag[2c], lo at frag[2c+1])
        float16 acc0, acc1;
        #pragma unroll
        for (int i = 0; i < 16; ++i) { acc0[i] = 0.0f; acc1[i] = 0.0f; }
        #pragma unroll
        for (int c = 0; c < 8; ++c) {
            int kst = ks4 * 8 + c;
            int slot = swz(lane, kst);
            uint4 pl = *(const uint4*)&ldsu[VF0 + (kst * 64 + slot) * 4];
            uint4 ph = *(const uint4*)&ldsu[VF1 + (kst * 64 + slot) * 4];
            short8 Ahi, Alo;
            unpack_frag(pl, ph, Ahi, Alo);
            acc0 = __builtin_amdgcn_mfma_f32_32x32x16_bf16(Ahi, frag[2 * c],     acc0, 0, 0, 0);
            acc1 = __builtin_amdgcn_mfma_f32_32x32x16_bf16(Alo, frag[2 * c],     acc1, 0, 0, 0);
            acc1 = __builtin_amdgcn_mfma_f32_32x32x16_bf16(Ahi, frag[2 * c + 1], acc1, 0, 0, 0);
        }

        // ---- overwrite frag with W for this substep's GEMM2 (L2/L1-resident;
        //      latency hidden under atomics + B1 + g-phase + B2). Single-array
        //      time-share: U and W can never be simultaneously allocated.
        asm volatile("" : "+s"(wop));
        {
            const short8* wp = (const short8*)wop;
            #pragma unroll
            for (int i = 0; i < 16; ++i)
                frag[i] = wp[(wb + i) * 64 + lane];
        }

        {
            int kcol = nt1 * 32 + (lane & 31);
            #pragma unroll
            for (int r = 0; r < 16; ++r) {
                int m = (r & 3) + 8 * (r >> 2) + 4 * rhalf;
                atomicAdd(&lds[HB + m * 68 + kcol], acc0[r] + acc1[r]);
            }
        }
        __syncthreads();   // B1: h complete

        // ---- g = h*h, split, write g-frags (one b128); zero h cell for next sub
        {
            int grow = t >> 4;
            int k4 = (t & 15) * 4;
            float4 h4 = *(const float4*)&lds[HB + grow * 68 + k4];
            float4 z4; z4.x = 0.0f; z4.y = 0.0f; z4.z = 0.0f; z4.w = 0.0f;
            *(float4*)&lds[HB + grow * 68 + k4] = z4;   // read-then-zero (thread-private cell)
            uint4 gp;
            gp.x = pack_split(h4.x * h4.x);
            gp.y = pack_split(h4.y * h4.y);
            gp.z = pack_split(h4.z * h4.z);
            gp.w = pack_split(h4.w * h4.w);
            int kst2 = k4 >> 4, lb2 = (k4 >> 3) & 1, jb = k4 & 7;
            int slot2 = swz(grow + 32 * lb2, kst2);
            *(uint4*)&ldsu[((jb >> 2) ? GF1 : GF0) + (kst2 * 64 + slot2) * 4] = gp;
        }
        __syncthreads();   // B2: g-frags ready (also orders HB zero before next atomics)

        // ---- GEMM2: christ tiles 2w, 2w+1 over K=64
        //      (frag holds W: hi at frag[nt*8+2kk], lo at frag[nt*8+2kk+1])
        float16 cA, cB;
        #pragma unroll
        for (int i = 0; i < 16; ++i) { cA[i] = 0.0f; cB[i] = 0.0f; }
        #pragma unroll
        for (int kk = 0; kk < 4; ++kk) {
            int slot = swz(lane, kk);
            uint4 pl = *(const uint4*)&ldsu[GF0 + (kk * 64 + slot) * 4];
            uint4 ph = *(const uint4*)&ldsu[GF1 + (kk * 64 + slot) * 4];
            short8 Ahi, Alo;
            unpack_frag(pl, ph, Ahi, Alo);
            cA = __builtin_amdgcn_mfma_f32_32x32x16_bf16(Ahi, frag[2 * kk],         cA, 0, 0, 0);
            cB = __builtin_amdgcn_mfma_f32_32x32x16_bf16(Ahi, frag[8 + 2 * kk],     cB, 0, 0, 0);
            cA = __builtin_amdgcn_mfma_f32_32x32x16_bf16(Alo, frag[2 * kk],         cA, 0, 0, 0);
            cB = __builtin_amdgcn_mfma_f32_32x32x16_bf16(Alo, frag[8 + 2 * kk],     cB, 0, 0, 0);
            cA = __builtin_amdgcn_mfma_f32_32x32x16_bf16(Ahi, frag[2 * kk + 1],     cA, 0, 0, 0);
            cB = __builtin_amdgcn_mfma_f32_32x32x16_bf16(Ahi, frag[8 + 2 * kk + 1], cB, 0, 0, 0);
        }

        // ---- refill frag with U for next substep's GEMM1 (hidden under
        //      epilogue VALU + vf_stores + B0 wait)
        if (sub != 11) {
            asm volatile("" : "+s"(uop));
            const short8* up = (const short8*)uop;
            #pragma unroll
            for (int i = 0; i < 16; ++i)
                frag[i] = up[(ub + i) * 64 + lane];
        }

        // ---- epilogue: v += ddt*(f - christ); x = wrap(x + xc*v) (+ fused c1)
        #pragma unroll
        for (int nt = 0; nt < 2; ++nt) {
            #pragma unroll
            for (int r = 0; r < 16; ++r) {
                int m = (r & 3) + 8 * (r >> 2) + 4 * rhalf;
                float fv = lds[FB + m * 516 + cg[nt]];
                float christ = (nt == 0) ? cA[r] : cB[r];
                float vn = vst[nt][r] + ddt * (fv - christ);
                vst[nt][r] = vn;
                float xn = wrap_torus(xst[nt][r] + xc * vn);
                if (dbl) xn = wrap_torus(xn + c1dt * vn);
                xst[nt][r] = xn;
            }
        }

        // ---- write new v splits for next substep
        if (sub != 11) {
            #pragma unroll
            for (int nt = 0; nt < 2; ++nt) {
                #pragma unroll
                for (int r = 0; r < 16; ++r) {
                    int m = (r & 3) + 8 * (r >> 2) + 4 * rhalf;
                    vf_store(ldsu, m, cg[nt], pack_split(vst[nt][r]));
                }
            }
        }
    }

    // ---- store outputs
    #pragma unroll
    for (int nt = 0; nt < 2; ++nt) {
        #pragma unroll
        for (int r = 0; r < 16; ++r) {
            int rrow = (r & 3) + 8 * (r >> 2) + 4 * rhalf;
            size_t idx = (size_t)(R0 + rrow) * 512 + cg[nt];
            xout[idx] = xst[nt][r];
            vout[idx] = vst[nt][r];
        }
    }
}

extern "C" void kernel_launch(void* const* d_in, const int* in_sizes, int n_in,
                              void* d_out, int out_size, void* d_ws, size_t ws_size,
                              hipStream_t stream) {
    const float* x = (const float*)d_in[0];
    const float* v = (const float*)d_in[1];
    const float* f = (const float*)d_in[2];
    const float* U = (const float*)d_in[3];
    const float* W = (const float*)d_in[4];

    float* xout = (float*)d_out;
    float* vout = xout + (size_t)32768 * 512;

    unsigned short* usw = (unsigned short*)d_ws;               // 128 KiB
    unsigned short* wsw = usw + 65536;                          // 128 KiB

    fr_prep<<<32, 256, 0, stream>>>(U, W, usw, wsw);

    hipFuncSetAttribute(reinterpret_cast<const void*>(fr_mfma),
                        hipFuncAttributeMaxDynamicSharedMemorySize, LDS_BYTES);
    fr_mfma<<<1024, NTH, LDS_BYTES, stream>>>(
        x, v, f, (const short8*)usw, (const short8*)wsw, xout, vout);
}